// Round 1
// 243.428 us; speedup vs baseline: 1.0268x; 1.0268x over previous
//
#include <hip/hip_runtime.h>

#define NN 20000

typedef _Float16 f16x2 __attribute__((ext_vector_type(2)));
typedef unsigned short u16x2 __attribute__((ext_vector_type(2)));

union U32H2 { unsigned int u; f16x2 h; };
union U32S2 { unsigned int u; u16x2 s; };

__device__ __forceinline__ f16x2 bc_h2(unsigned int u) { U32H2 x; x.u = u; return x.h; }
__device__ __forceinline__ unsigned int dup_h(float v) {
    _Float16 h = (_Float16)v;
    unsigned short b = __builtin_bit_cast(unsigned short, h);
    return ((unsigned int)b << 16) | b;
}
// packed f32->f16 convert, result as raw u32 (v_cvt_pkrtz_f16_f32)
__device__ __forceinline__ unsigned int pkrtz_u32(float a, float b) {
    return __builtin_bit_cast(unsigned int, __builtin_amdgcn_cvt_pkrtz(a, b));
}

// ---------------- setup: prep (block 20) + pack (blocks 0..19) ----------------
__global__ __launch_bounds__(1024) void setup_kernel(const float* __restrict__ W,
                                                     const float* __restrict__ a0,
                                                     unsigned int* __restrict__ pi_t_pk,
                                                     unsigned int* __restrict__ pi1_pk,
                                                     unsigned int* __restrict__ pi2_pk,
                                                     unsigned int* __restrict__ T0) {
    const int t = threadIdx.x;
    if (blockIdx.x != 20) {
        // pack a0 fp32 (B,N) planes -> u8x4 table
        int i = blockIdx.x * 1024 + t;
        if (i < NN) {
            unsigned int b0 = __float2uint_rn(__saturatef(a0[i]) * 255.0f);
            unsigned int b1 = __float2uint_rn(__saturatef(a0[NN + i]) * 255.0f);
            unsigned int b2 = __float2uint_rn(__saturatef(a0[2 * NN + i]) * 255.0f);
            unsigned int b3 = __float2uint_rn(__saturatef(a0[3 * NN + i]) * 255.0f);
            T0[i] = b0 | (b1 << 8) | (b2 << 16) | (b3 << 24);
        }
        return;
    }
    // prep: softmax(W) -> packed-f16 pi tables
    __shared__ float red[1024];
    __shared__ float piL[4096];
    float4 wv = ((const float4*)W)[t];
    float m = fmaxf(fmaxf(wv.x, wv.y), fmaxf(wv.z, wv.w));
    red[t] = m; __syncthreads();
    for (int s = 512; s > 0; s >>= 1) {
        if (t < s) red[t] = fmaxf(red[t], red[t + s]);
        __syncthreads();
    }
    m = red[0];
    __syncthreads();
    float e0 = expf(wv.x - m), e1 = expf(wv.y - m);
    float e2 = expf(wv.z - m), e3 = expf(wv.w - m);
    red[t] = e0 + e1 + e2 + e3;
    __syncthreads();
    for (int s = 512; s > 0; s >>= 1) {
        if (t < s) red[t] += red[t + s];
        __syncthreads();
    }
    float inv = 1.0f / red[0];
    float p[4] = { e0 * inv, e1 * inv, e2 * inv, e3 * inv };
#pragma unroll
    for (int i = 0; i < 4; i++) {
        int f = t * 4 + i;
        piL[f] = p[i];
        pi_t_pk[(f & 63) * 64 + (f >> 6)] = dup_h(p[i]);  // transposed [k][j]
    }
    __syncthreads();
    if (t < 64) {
        float s = 0.f;
        for (int k = 0; k < 64; k++) s += piL[t * 64 + k];
        pi1_pk[t] = dup_h(s);
    } else if (t < 128) {
        int k = t - 64;
        float s = 0.f;
        for (int j = 0; j < 64; j++) s += piL[j * 64 + k];
        pi2_pk[k] = dup_h(s);
    }
}

// ---------------- fused predicate_forward iteration ----------------
// Phase 1 is lane-serial over w: each lane owns one (row, n) output and
// iterates the 8 window pairs itself (16 gathers + ~100 VALU / output),
// replacing the 8-lane DPP octmax scheme (~256 lane-ops / output).
template <int ITER>
__global__ __launch_bounds__(1024, 4) void fused_iter(
    const unsigned int* __restrict__ Tsrc,
    const int* __restrict__ X1, const int* __restrict__ X2,
    const unsigned int* __restrict__ pi_t_pk,
    const unsigned int* __restrict__ pi1_pk,
    const unsigned int* __restrict__ pi2_pk,
    const float* __restrict__ a0,
    unsigned int* __restrict__ Tdst, float* __restrict__ outP) {
    __shared__ unsigned int tab[NN];          // 80,000 B
    __shared__ unsigned int Ft[128][40][2];   // 40,960 B  [row][col][bpair]
    __shared__ float redp[8][64][4];          // 8,192 B
    __shared__ float a_sm[64][4];             // 1,024 B

    const int t = threadIdx.x;
    for (int i = t; i < NN; i += 1024) tab[i] = Tsrc[i];

    const int bid = (int)blockIdx.x;
    const int bstart = bid < 32 ? bid * 79 : 32 * 79 + (bid - 32) * 78;
    const int bcnt = bid < 32 ? 79 : 78;
    const int c0 = (bcnt + 1) >> 1;  // 40 or 39

    const int wid = t >> 6, lane = t & 63;
    // wave-constant values forced into SGPRs
    const int widu = __builtin_amdgcn_readfirstlane(wid);
    const int r8 = lane >> 3, n8 = lane & 7;
    const int row = widu * 8 + r8;            // 0..127 (waves 0..7 -> X1, 8..15 -> X2)
    const int k = row & 63;
    const int q = t >> 7, bp = (t >> 6) & 1, n_l = t & 63;
    const int qu = __builtin_amdgcn_readfirstlane(q);

    // per-lane X row base: 64 B of indices per (k, n)  (16 x int32)
    const char* Xrow = (const char*)(widu >= 8 ? X2 : X1)
                     + (size_t)((unsigned)(k * NN)) * 64u;

    __syncthreads();

    for (int ch = 0; ch < 2; ++ch) {
        const int nb = bstart + (ch ? c0 : 0);
        const int cn = ch ? (bcnt - c0) : c0;

        // ---------------- phase 1: lane-serial clause gathers ----------------
        {
            const float sc = 1.0f / 65025.0f;
            int loff[5];
#pragma unroll
            for (int oc = 0; oc < 5; ++oc) {
                int n = nb + oc * 8 + n8;
                int nc = n < NN ? n : NN - 1;   // clamp: col>=cn lanes read safe addr
                loff[oc] = nc * 64;
            }
            int4 qa[4], qb[4];
#pragma unroll
            for (int i = 0; i < 4; ++i) qa[i] = *(const int4*)(Xrow + loff[0] + i * 16);

#pragma unroll
            for (int oc = 0; oc < 5; ++oc) {
                if (oc < 4) {
#pragma unroll
                    for (int i = 0; i < 4; ++i)
                        qb[i] = *(const int4*)(Xrow + loff[oc + 1] + i * 16);
                }
                // 16 independent gathers for this output element
                unsigned int g[16];
                const int* qi = (const int*)qa;
#pragma unroll
                for (int p = 0; p < 16; ++p) g[p] = tab[qi[p]];

                U32S2 me, mo; me.u = 0u; mo.u = 0u;
#pragma unroll
                for (int p = 0; p < 8; ++p) {
                    unsigned int ax = g[2 * p], bx = g[2 * p + 1];
                    unsigned int ea = ax & 0x00FF00FFu;
                    unsigned int oa = __builtin_amdgcn_perm(0u, ax, 0x0C030C01u); // (ax>>8)&0x00FF00FF
                    unsigned int eb = bx & 0x00FF00FFu;
                    unsigned int ob = __builtin_amdgcn_perm(0u, bx, 0x0C030C01u);
                    U32S2 pe, po, xb;
                    pe.u = ea; xb.u = eb; pe.s = pe.s * xb.s;   // v_pk_mul_lo_u16
                    po.u = oa; xb.u = ob; po.s = po.s * xb.s;
                    me.s = __builtin_elementwise_max(me.s, pe.s);
                    mo.s = __builtin_elementwise_max(mo.s, po.s);
                }
                int col = oc * 8 + n8;
                if (col < cn) {
                    float f0 = (float)(me.u & 0xFFFFu) * sc;   // b0
                    float f1 = (float)(mo.u & 0xFFFFu) * sc;   // b1
                    float f2 = (float)(me.u >> 16) * sc;       // b2
                    float f3 = (float)(mo.u >> 16) * sc;       // b3
                    *(uint2*)&Ft[row][col][0] =
                        make_uint2(pkrtz_u32(f0, f1), pkrtz_u32(f2, f3));
                }
#pragma unroll
                for (int i = 0; i < 4; ++i) qa[i] = qb[i];
            }
        }
        __syncthreads();

        // ---------------- phase 2: bilinear (Ft read once per k) ----------------
        {
            float part0 = 0.f, part1 = 0.f;
            if (n_l < cn) {
                f16x2 zero = {(_Float16)0, (_Float16)0};
                f16x2 f1v[8];
                f16x2 eu = zero;
#pragma unroll
                for (int jj = 0; jj < 8; ++jj) {
                    f1v[jj] = bc_h2(Ft[qu * 8 + jj][n_l][bp]);
                    eu += bc_h2(pi1_pk[qu * 8 + jj]) * f1v[jj];  // s_load
                }
                f16x2 euv = zero, ev = zero;
#pragma unroll 8
                for (int k2 = 0; k2 < 64; ++k2) {
                    f16x2 f2 = bc_h2(Ft[64 + k2][n_l][bp]);
                    const uint4* pt = (const uint4*)(pi_t_pk + k2 * 64 + qu * 8);
                    uint4 w0 = pt[0], w1 = pt[1];  // all-scalar addr -> s_load_dwordx4
                    f16x2 ts = bc_h2(w0.x) * f1v[0] + bc_h2(w0.y) * f1v[1] +
                               bc_h2(w0.z) * f1v[2] + bc_h2(w0.w) * f1v[3] +
                               bc_h2(w1.x) * f1v[4] + bc_h2(w1.y) * f1v[5] +
                               bc_h2(w1.z) * f1v[6] + bc_h2(w1.w) * f1v[7];
                    euv += f2 * ts;
                    if (qu == 0) ev += bc_h2(pi2_pk[k2]) * f2;
                }
                part0 = (float)eu[0] - (float)euv[0];
                part1 = (float)eu[1] - (float)euv[1];
                if (qu == 0) {
                    part0 += (float)ev[0];
                    part1 += (float)ev[1];
                }
            }
            *(float2*)&redp[q][n_l][bp * 2] = make_float2(part0, part1);
        }
        __syncthreads();

        // ---------------- combine + soft-OR update ----------------
        if (t < 256) {
            int n = t & 63, b = t >> 6;
            if (n < cn) {
                float d = 0.f;
#pragma unroll
                for (int q8 = 0; q8 < 8; ++q8) d += redp[q8][n][b];
                int gn = nb + n;
                float ap;
                if (ITER == 1) ap = a0[(size_t)b * NN + gn];
                else ap = (float)((tab[gn] >> (8 * b)) & 255u) * (1.0f / 255.0f);
                float an = 1.0f - (1.0f - ap) * (1.0f - d);
                if (ITER == 1) a_sm[n][b] = an;
                else outP[(size_t)b * NN + gn] = an;
            }
        }
        __syncthreads();
        if (ITER == 1 && t < 64 && t < cn) {
            unsigned int b0 = __float2uint_rn(__saturatef(a_sm[t][0]) * 255.0f);
            unsigned int b1 = __float2uint_rn(__saturatef(a_sm[t][1]) * 255.0f);
            unsigned int b2 = __float2uint_rn(__saturatef(a_sm[t][2]) * 255.0f);
            unsigned int b3 = __float2uint_rn(__saturatef(a_sm[t][3]) * 255.0f);
            Tdst[nb + t] = b0 | (b1 << 8) | (b2 << 16) | (b3 << 24);
        }
        __syncthreads();
    }
}

extern "C" void kernel_launch(void* const* d_in, const int* in_sizes, int n_in,
                              void* d_out, int out_size, void* d_ws, size_t ws_size,
                              hipStream_t stream) {
    const float* a0 = (const float*)d_in[0];
    const float* W = (const float*)d_in[1];
    const int* X1 = (const int*)d_in[2];   // int64 in ref -> int32 on device
    const int* X2 = (const int*)d_in[3];
    float* out = (float*)d_out;

    // ws: (unused @0, 16,384) | pi_t_pk @16,384 (16,384) | pi1_pk @32,768 (256)
    // | pi2_pk @33,024 (256) | T0 @33,280 (80,000) | T1 @113,280 (80,000)
    if (ws_size < (size_t)193280) return;
    unsigned int* pi_t   = (unsigned int*)((char*)d_ws + 16384);
    unsigned int* pi1_pk = (unsigned int*)((char*)d_ws + 32768);
    unsigned int* pi2_pk = (unsigned int*)((char*)d_ws + 33024);
    unsigned int* T0     = (unsigned int*)((char*)d_ws + 33280);
    unsigned int* T1     = (unsigned int*)((char*)d_ws + 113280);

    setup_kernel<<<21, 1024, 0, stream>>>(W, a0, pi_t, pi1_pk, pi2_pk, T0);
    fused_iter<1><<<256, 1024, 0, stream>>>(T0, X1, X2, pi_t, pi1_pk, pi2_pk,
                                            a0, T1, nullptr);
    fused_iter<2><<<256, 1024, 0, stream>>>(T1, X1, X2, pi_t, pi1_pk, pi2_pk,
                                            nullptr, nullptr, out);
}